// Round 11
// baseline (142.348 us; speedup 1.0000x reference)
//
#include <hip/hip_runtime.h>
#include <stdint.h>

#define THREADS 512
#define NE 8
#define BB 4
#define SS 512
#define KK 2
#define II 1024
#define DD 2048
#define NTOK (BB * SS)         // 2048
#define NASSIGN (BB * KK * SS) // 4096

// convert: one 8-float chunk (32B in / 16B out) per thread, R4-proven
#define CH_X (NTOK * II / 8)      // 262144
#define CH_P (NE * DD * II / 8)   // 2097152
#define CB_X (CH_X / 256)         // 1024 blocks
#define CB_P (CH_P / 256)         // 8192 blocks
#define CB_TOTAL (CB_X + 2 * CB_P) // 17408 blocks

typedef unsigned short u16;
typedef __attribute__((ext_vector_type(8))) __bf16 bf16x8;
typedef __attribute__((ext_vector_type(4))) float f32x4;
typedef __attribute__((ext_vector_type(4))) unsigned int u32x4;

__device__ __forceinline__ u16 f32_to_bf16(float f) {
    unsigned int u = __builtin_bit_cast(unsigned int, f);
    unsigned int r = u + 0x7FFFu + ((u >> 16) & 1u);
    return (u16)(r >> 16);
}

__device__ __forceinline__ void gload16(const void* g, void* l) {
    __builtin_amdgcn_global_load_lds(
        (const __attribute__((address_space(1))) unsigned int*)g,
        (__attribute__((address_space(3))) unsigned int*)l, 16, 0, 0);
}

#define BARRIER() do { \
    __builtin_amdgcn_sched_barrier(0); \
    __builtin_amdgcn_s_barrier(); \
    __builtin_amdgcn_sched_barrier(0); } while (0)

// ---------------- setup: bucket assignments by expert, 256-row tiles -------
__global__ void setup_kernel(const void* __restrict__ ens_raw,
                             const float* __restrict__ weights,
                             int* __restrict__ meta,
                             int* __restrict__ tok,
                             float* __restrict__ wgt) {
    __shared__ int s_cnt[NE];
    __shared__ int s_cur[NE];
    __shared__ int s_flag;
    const int t = threadIdx.x;
    if (t < NE) s_cnt[t] = 0;
    if (t == 0) s_flag = 0;
    __syncthreads();

    // dtype detect: int64 ensembles (vals 0..7) -> all odd 32-bit words zero
    const unsigned int* w32 = (const unsigned int*)ens_raw;
    unsigned int f = 0;
    for (int i = t; i < NASSIGN / 2; i += 256) f |= w32[2 * i + 1];
    if (f) atomicOr(&s_flag, 1);
    __syncthreads();
    const bool is32 = (s_flag != 0);
    const int* e32 = (const int*)ens_raw;
    const long long* e64 = (const long long*)ens_raw;

    for (int a = t; a < NASSIGN; a += 256) {
        int e = is32 ? e32[a] : (int)e64[a];
        atomicAdd(&s_cnt[e & 7], 1);
    }
    __syncthreads();

    if (t == 0) {
        int pb = 0, nt = 0;
        for (int e = 0; e < NE; e++) {
            int c = s_cnt[e];
            meta[8 + e] = c;
            meta[16 + e] = pb;
            s_cur[e] = pb;
            int n128 = (c + 127) >> 7;
            int pe = pb + n128 * 128;
            for (int i2 = 0; i2 < n128; i2 += 2) {
                meta[32 + nt] = e;             // expert
                meta[64 + nt] = pb + i2 * 128; // slot base (256-row tile)
                meta[96 + nt] = pb + c;        // real end (atomic guard)
                meta[128 + nt] = pe;           // pad end  (h-write guard)
                nt++;
            }
            pb = pe;
        }
        meta[0] = nt;
        meta[1] = pb;
    }
    __syncthreads();

    for (int a = t; a < NASSIGN; a += 256) {
        int e = is32 ? e32[a] : (int)e64[a];
        e &= 7;
        int slot = atomicAdd(&s_cur[e], 1);
        int b = a >> 10;
        int s = a & (SS - 1);
        tok[slot] = b * SS + s;
        wgt[slot] = weights[a];
    }
    __syncthreads();

    // pad fill
    for (int e = 0; e < NE; e++) {
        int st = meta[16 + e] + meta[8 + e];
        int en = (e < NE - 1) ? meta[16 + e + 1] : meta[1];
        for (int i = st + t; i < en; i += 256) {
            tok[i] = 0;
            wgt[i] = 0.f;
        }
    }
}

// ---------------- f32 -> bf16: R4-proven (1 chunk/thread, 16B store) -------
__global__ __launch_bounds__(256)
void convert3(const float* __restrict__ x,
              const float* __restrict__ pin,
              const float* __restrict__ pout,
              u16* __restrict__ xb,
              u16* __restrict__ pb1,
              u16* __restrict__ pb2) {
    const int b = blockIdx.x;
    const float* s;
    u16* d;
    int base;
    if (b < CB_X)            { s = x;    d = xb;  base = b << 8; }
    else if (b < CB_X + CB_P){ s = pin;  d = pb1; base = (b - CB_X) << 8; }
    else                     { s = pout; d = pb2; base = (b - CB_X - CB_P) << 8; }
    const size_t k = (size_t)base + threadIdx.x;
    const f32x4* s4 = (const f32x4*)s;
    f32x4 a = __builtin_nontemporal_load(&s4[2 * k]);
    f32x4 c = __builtin_nontemporal_load(&s4[2 * k + 1]);
    union { u16 u[8]; u32x4 v; } o;
    o.u[0] = f32_to_bf16(a[0]); o.u[1] = f32_to_bf16(a[1]);
    o.u[2] = f32_to_bf16(a[2]); o.u[3] = f32_to_bf16(a[3]);
    o.u[4] = f32_to_bf16(c[0]); o.u[5] = f32_to_bf16(c[1]);
    o.u[6] = f32_to_bf16(c[2]); o.u[7] = f32_to_bf16(c[3]);
    *(u32x4*)(d + 8 * k) = o.v;
}

// ---------------- gemm1: 256x256 tile, BK=64, 2-buf drain template ---------
// h[slot] = relu(x_bf[tok[slot]] @ pin_bf^T), K=1024, NT=16
// 8 waves as 2M x 4N: wave -> 128 rows x 64 cols. LDS 2 x 64KB = 128KB.
__global__ __launch_bounds__(THREADS, 2)
void gemm1(const u16* __restrict__ Abase,
           const u16* __restrict__ Bbase,
           const int* __restrict__ meta,
           const int* __restrict__ tok,
           u16* __restrict__ hdst) {
    constexpr int NT = II / 64;       // 16
    constexpr int ASZ = 256 * 64 * 2; // 32768
    constexpr int BUFSZ = 2 * ASZ;    // A + B
    __shared__ char smem[2 * BUFSZ];  // 131072

    const int lid = blockIdx.x;
    const int g = lid & 7;
    const int i = lid >> 3;
    const int tile = g + 8 * (i % 3); // balanced across XCDs when nt<24
    const int colt = i / 3;           // 0..7
    if (tile >= meta[0]) return;

    const int e     = meta[32 + tile];
    const int sbase = meta[64 + tile];
    const int wend  = meta[128 + tile];
    const int padmax = meta[1];
    const int colbase = colt * 256;

    const int tid = threadIdx.x;
    const int lane = tid & 63;
    const int wv = tid >> 6;
    const int wr = wv >> 2;  // 0..1 (128-row stripes)
    const int wc = wv & 3;   // 0..3 (64-col stripes)

    const u16* Bp = Bbase + (size_t)e * (size_t)(DD * II) + (size_t)colbase * II;

    int aoff[4], boff[4], cdst[4];
#pragma unroll
    for (int j = 0; j < 4; j++) {
        int c = j * 512 + tid;
        int row = c >> 3;
        int s = (c & 7) ^ (row & 7);
        cdst[j] = c * 16;
        int slot = sbase + row;
        if (slot > padmax - 1) slot = padmax - 1; // clamp (rows discarded)
        aoff[j] = tok[slot] * II + s * 8;
        boff[j] = row * II + s * 8;
    }

    f32x4 acc[8][4];
#pragma unroll
    for (int m = 0; m < 8; m++)
#pragma unroll
        for (int n = 0; n < 4; n++)
            acc[m][n] = (f32x4){0.f, 0.f, 0.f, 0.f};

    auto STAGE = [&](int kt, char* buf) {
        const int kof = kt * 64;
#pragma unroll
        for (int j = 0; j < 4; j++)
            gload16(Abase + aoff[j] + kof, buf + cdst[j]);
#pragma unroll
        for (int j = 0; j < 4; j++)
            gload16(Bp + boff[j] + kof, buf + ASZ + cdst[j]);
    };

    auto COMPUTE = [&](const char* buf) {
        const u16* As = (const u16*)buf;
        const u16* Bs = (const u16*)(buf + ASZ);
#pragma unroll
        for (int kk = 0; kk < 2; kk++) {
            bf16x8 a[8], b[4];
#pragma unroll
            for (int m = 0; m < 8; m++) {
                int row = wr * 128 + m * 16 + (lane & 15);
                int slot = (kk * 4 + (lane >> 4)) ^ (row & 7);
                a[m] = *(const bf16x8*)&As[row * 64 + slot * 8];
            }
#pragma unroll
            for (int n = 0; n < 4; n++) {
                int col = wc * 64 + n * 16 + (lane & 15);
                int slot = (kk * 4 + (lane >> 4)) ^ (col & 7);
                b[n] = *(const bf16x8*)&Bs[col * 64 + slot * 8];
            }
            asm volatile("s_waitcnt lgkmcnt(0)" ::: "memory");
            __builtin_amdgcn_sched_barrier(0);
            __builtin_amdgcn_s_setprio(1);
#pragma unroll
            for (int m = 0; m < 8; m++)
#pragma unroll
                for (int n = 0; n < 4; n++)
                    acc[m][n] = __builtin_amdgcn_mfma_f32_16x16x32_bf16(
                        a[m], b[n], acc[m][n], 0, 0, 0);
            __builtin_amdgcn_s_setprio(0);
        }
    };

    char* buf0 = smem;
    char* buf1 = smem + BUFSZ;

    STAGE(0, buf0);
    asm volatile("s_waitcnt vmcnt(0)" ::: "memory");
    BARRIER();

#pragma unroll 1
    for (int t = 0; t < NT; ++t) {
        char* cur = (t & 1) ? buf1 : buf0;
        char* nxt = (t & 1) ? buf0 : buf1;
        const bool st = (t + 1 < NT);
        if (st) STAGE(t + 1, nxt);
        COMPUTE(cur);
        if (st) asm volatile("s_waitcnt vmcnt(0)" ::: "memory");
        BARRIER();
    }

#pragma unroll
    for (int m = 0; m < 8; m++) {
#pragma unroll
        for (int r = 0; r < 4; r++) {
            int row = wr * 128 + m * 16 + (lane >> 4) * 4 + r;
            int slot = sbase + row;
            if (slot < wend) { // stay inside this expert's pad region
                size_t ro = (size_t)slot * DD;
#pragma unroll
                for (int n = 0; n < 4; n++) {
                    int col = colbase + wc * 64 + n * 16 + (lane & 15);
                    float v = acc[m][n][r];
                    v = v > 0.f ? v : 0.f;
                    hdst[ro + col] = f32_to_bf16(v);
                }
            }
        }
    }
}

// ---------------- gemm2: 256x256 tile, split-K x2, 2-buf drain template ----
// out[tok[slot]] += wgt * (h[slot] @ pout_bf^T); each block does K-half 1024
__global__ __launch_bounds__(THREADS, 2)
void gemm2(const u16* __restrict__ Abase,
           const u16* __restrict__ Bbase,
           const int* __restrict__ meta,
           const int* __restrict__ tok,
           const float* __restrict__ wgt,
           float* __restrict__ outdst) {
    constexpr int NT = 16;            // 1024 K per block
    constexpr int ASZ = 256 * 64 * 2; // 32768
    constexpr int BUFSZ = 2 * ASZ;    // A + B
    __shared__ char smem[2 * BUFSZ];  // 131072

    // decode: XCD g x 3 tile-groups x 4 colt x 2 ksplit = 192 blocks
    const int lid = blockIdx.x;
    const int g = lid & 7;
    const int i = lid >> 3;
    const int tile = g + 8 * (i % 3);
    const int rest = i / 3;   // 0..7
    const int colt = rest & 3;
    const int ks = rest >> 2; // 0..1
    if (tile >= meta[0]) return;

    const int e     = meta[32 + tile];
    const int sbase = meta[64 + tile];
    const int rend  = meta[96 + tile];
    const int padmax = meta[1];
    const int colbase = colt * 256;
    const int kbase = ks * 1024;

    const int tid = threadIdx.x;
    const int lane = tid & 63;
    const int wv = tid >> 6;
    const int wr = wv >> 2;  // 0..1 (128-row stripes)
    const int wc = wv & 3;   // 0..3 (64-col stripes)

    const u16* Bp = Bbase + (size_t)e * (size_t)(DD * II) + (size_t)colbase * DD;

    int aoff[4], boff[4], cdst[4];
#pragma unroll
    for (int j = 0; j < 4; j++) {
        int c = j * 512 + tid;
        int row = c >> 3;
        int s = (c & 7) ^ (row & 7);
        cdst[j] = c * 16;
        int slot = sbase + row;
        if (slot > padmax - 1) slot = padmax - 1;
        aoff[j] = slot * DD + kbase + s * 8;
        boff[j] = row * DD + kbase + s * 8;
    }

    f32x4 acc[8][4];
#pragma unroll
    for (int m = 0; m < 8; m++)
#pragma unroll
        for (int n = 0; n < 4; n++)
            acc[m][n] = (f32x4){0.f, 0.f, 0.f, 0.f};

    auto STAGE = [&](int kt, char* buf) {
        const int kof = kt * 64;
#pragma unroll
        for (int j = 0; j < 4; j++)
            gload16(Abase + aoff[j] + kof, buf + cdst[j]);
#pragma unroll
        for (int j = 0; j < 4; j++)
            gload16(Bp + boff[j] + kof, buf + ASZ + cdst[j]);
    };

    auto COMPUTE = [&](const char* buf) {
        const u16* As = (const u16*)buf;
        const u16* Bs = (const u16*)(buf + ASZ);
#pragma unroll
        for (int kk = 0; kk < 2; kk++) {
            bf16x8 a[8], b[4];
#pragma unroll
            for (int m = 0; m < 8; m++) {
                int row = wr * 128 + m * 16 + (lane & 15);
                int slot = (kk * 4 + (lane >> 4)) ^ (row & 7);
                a[m] = *(const bf16x8*)&As[row * 64 + slot * 8];
            }
#pragma unroll
            for (int n = 0; n < 4; n++) {
                int col = wc * 64 + n * 16 + (lane & 15);
                int slot = (kk * 4 + (lane >> 4)) ^ (col & 7);
                b[n] = *(const bf16x8*)&Bs[col * 64 + slot * 8];
            }
            asm volatile("s_waitcnt lgkmcnt(0)" ::: "memory");
            __builtin_amdgcn_sched_barrier(0);
            __builtin_amdgcn_s_setprio(1);
#pragma unroll
            for (int m = 0; m < 8; m++)
#pragma unroll
                for (int n = 0; n < 4; n++)
                    acc[m][n] = __builtin_amdgcn_mfma_f32_16x16x32_bf16(
                        a[m], b[n], acc[m][n], 0, 0, 0);
            __builtin_amdgcn_s_setprio(0);
        }
    };

    char* buf0 = smem;
    char* buf1 = smem + BUFSZ;

    STAGE(0, buf0);
    asm volatile("s_waitcnt vmcnt(0)" ::: "memory");
    BARRIER();

#pragma unroll 1
    for (int t = 0; t < NT; ++t) {
        char* cur = (t & 1) ? buf1 : buf0;
        char* nxt = (t & 1) ? buf0 : buf1;
        const bool st = (t + 1 < NT);
        if (st) STAGE(t + 1, nxt);
        COMPUTE(cur);
        if (st) asm volatile("s_waitcnt vmcnt(0)" ::: "memory");
        BARRIER();
    }

#pragma unroll
    for (int m = 0; m < 8; m++) {
#pragma unroll
        for (int r = 0; r < 4; r++) {
            int row = wr * 128 + m * 16 + (lane >> 4) * 4 + r;
            int slot = sbase + row;
            if (slot < rend) { // skip padding rows
                float w = wgt[slot];
                size_t obase = (size_t)tok[slot] * II;
#pragma unroll
                for (int n = 0; n < 4; n++) {
                    int col = colbase + wc * 64 + n * 16 + (lane & 15);
                    atomicAdd(&outdst[obase + col], acc[m][n][r] * w);
                }
            }
        }
    }
}

// ---------------- launch ----------------
extern "C" void kernel_launch(void* const* d_in, const int* in_sizes, int n_in,
                              void* d_out, int out_size, void* d_ws, size_t ws_size,
                              hipStream_t stream) {
    const float* x = (const float*)d_in[0];
    const float* weights = (const float*)d_in[1];
    const void* ens = d_in[2];
    const float* pin = (const float*)d_in[3];
    const float* pout = (const float*)d_in[4];
    float* out = (float*)d_out;

    char* ws = (char*)d_ws;
    int*   meta    = (int*)(ws);            // 1 KB
    int*   tok     = (int*)(ws + 1024);     // 20 KB
    float* wgt     = (float*)(ws + 21504);  // 20 KB   -> 41984
    u16*   x_bf    = (u16*)(ws + 41984);    // 4 MB    -> 4236288
    u16*   pin_bf  = (u16*)(ws + 4236288);  // 33.5 MB -> 37790720
    u16*   pout_bf = (u16*)(ws + 37790720); // 33.5 MB -> 71345152
    u16*   h       = (u16*)(ws + 71345152); // 21 MB   -> 92316672 total

    setup_kernel<<<dim3(1), dim3(256), 0, stream>>>(ens, weights, meta, tok, wgt);

    hipMemsetAsync(d_out, 0, (size_t)out_size * sizeof(float), stream);

    convert3<<<dim3(CB_TOTAL), dim3(256), 0, stream>>>(
        x, pin, pout, x_bf, pin_bf, pout_bf);

    // gemm1: up to 24 tiles x 8 col-blocks (256-wide), XCD-interleaved
    gemm1<<<dim3(8 * 3 * 8), dim3(THREADS), 0, stream>>>(
        x_bf, pin_bf, meta, tok, h);

    // gemm2: up to 24 tiles x 4 col-blocks (256-wide) x split-K 2
    gemm2<<<dim3(8 * 3 * 8), dim3(THREADS), 0, stream>>>(
        h, pout_bf, meta, tok, wgt, out);
}

// Round 12
// 135.602 us; speedup vs baseline: 1.0497x; 1.0497x over previous
//
#include <hip/hip_runtime.h>
#include <stdint.h>

#define THREADS 512
#define NE 8
#define BB 4
#define SS 512
#define KK 2
#define II 1024
#define DD 2048
#define NTOK (BB * SS)         // 2048
#define NASSIGN (BB * KK * SS) // 4096

// convert: one 8-float chunk (32B in / 16B out) per thread
#define CH_X (NTOK * II / 8)      // 262144
#define CH_P (NE * DD * II / 8)   // 2097152
#define CB_X (CH_X / 256)         // 1024 blocks
#define CB_P (CH_P / 256)         // 8192 blocks
#define CB_TOTAL (CB_X + 2 * CB_P) // 17408 blocks

typedef unsigned short u16;
typedef __attribute__((ext_vector_type(8))) __bf16 bf16x8;
typedef __attribute__((ext_vector_type(4))) float f32x4;
typedef __attribute__((ext_vector_type(4))) unsigned int u32x4;

__device__ __forceinline__ u16 f32_to_bf16(float f) {
    unsigned int u = __builtin_bit_cast(unsigned int, f);
    unsigned int r = u + 0x7FFFu + ((u >> 16) & 1u);
    return (u16)(r >> 16);
}

__device__ __forceinline__ void gload16(const void* g, void* l) {
    __builtin_amdgcn_global_load_lds(
        (const __attribute__((address_space(1))) unsigned int*)g,
        (__attribute__((address_space(3))) unsigned int*)l, 16, 0, 0);
}

#define BARRIER() do { \
    __builtin_amdgcn_sched_barrier(0); \
    __builtin_amdgcn_s_barrier(); \
    __builtin_amdgcn_sched_barrier(0); } while (0)

// ---------------- setup: bucket assignments by expert, 256-row tiles -------
__global__ void setup_kernel(const void* __restrict__ ens_raw,
                             const float* __restrict__ weights,
                             int* __restrict__ meta,
                             int* __restrict__ tok,
                             float* __restrict__ wgt) {
    __shared__ int s_cnt[NE];
    __shared__ int s_cur[NE];
    __shared__ int s_flag;
    const int t = threadIdx.x;
    if (t < NE) s_cnt[t] = 0;
    if (t == 0) s_flag = 0;
    __syncthreads();

    // dtype detect: int64 ensembles (vals 0..7) -> all odd 32-bit words zero
    const unsigned int* w32 = (const unsigned int*)ens_raw;
    unsigned int f = 0;
    for (int i = t; i < NASSIGN / 2; i += 256) f |= w32[2 * i + 1];
    if (f) atomicOr(&s_flag, 1);
    __syncthreads();
    const bool is32 = (s_flag != 0);
    const int* e32 = (const int*)ens_raw;
    const long long* e64 = (const long long*)ens_raw;

    for (int a = t; a < NASSIGN; a += 256) {
        int e = is32 ? e32[a] : (int)e64[a];
        atomicAdd(&s_cnt[e & 7], 1);
    }
    __syncthreads();

    if (t == 0) {
        int pb = 0, nt = 0;
        for (int e = 0; e < NE; e++) {
            int c = s_cnt[e];
            meta[8 + e] = c;
            meta[16 + e] = pb;
            s_cur[e] = pb;
            int n128 = (c + 127) >> 7;
            int pe = pb + n128 * 128;
            for (int i2 = 0; i2 < n128; i2 += 2) {
                meta[32 + nt] = e;             // expert
                meta[64 + nt] = pb + i2 * 128; // slot base (256-row tile)
                meta[96 + nt] = pb + c;        // real end (atomic guard)
                meta[128 + nt] = pe;           // pad end  (h-write guard)
                nt++;
            }
            pb = pe;
        }
        meta[0] = nt;
        meta[1] = pb;
    }
    __syncthreads();

    for (int a = t; a < NASSIGN; a += 256) {
        int e = is32 ? e32[a] : (int)e64[a];
        e &= 7;
        int slot = atomicAdd(&s_cur[e], 1);
        int b = a >> 10;
        int s = a & (SS - 1);
        tok[slot] = b * SS + s;
        wgt[slot] = weights[a];
    }
    __syncthreads();

    // pad fill
    for (int e = 0; e < NE; e++) {
        int st = meta[16 + e] + meta[8 + e];
        int en = (e < NE - 1) ? meta[16 + e + 1] : meta[1];
        for (int i = st + t; i < en; i += 256) {
            tok[i] = 0;
            wgt[i] = 0.f;
        }
    }
}

// ---------------- f32 -> bf16: flat, nontemporal loads AND stores ----------
// (nontemporal store avoids read-for-ownership: R10 profile showed
//  FETCH_SIZE == WRITE_SIZE on warm replays = RFO traffic)
__global__ __launch_bounds__(256)
void convert3(const float* __restrict__ x,
              const float* __restrict__ pin,
              const float* __restrict__ pout,
              u16* __restrict__ xb,
              u16* __restrict__ pb1,
              u16* __restrict__ pb2) {
    const int b = blockIdx.x;
    const float* s;
    u16* d;
    int base;
    if (b < CB_X)            { s = x;    d = xb;  base = b << 8; }
    else if (b < CB_X + CB_P){ s = pin;  d = pb1; base = (b - CB_X) << 8; }
    else                     { s = pout; d = pb2; base = (b - CB_X - CB_P) << 8; }
    const size_t k = (size_t)base + threadIdx.x;
    const f32x4* s4 = (const f32x4*)s;
    f32x4 a = __builtin_nontemporal_load(&s4[2 * k]);
    f32x4 c = __builtin_nontemporal_load(&s4[2 * k + 1]);
    union { u16 u[8]; u32x4 v; } o;
    o.u[0] = f32_to_bf16(a[0]); o.u[1] = f32_to_bf16(a[1]);
    o.u[2] = f32_to_bf16(a[2]); o.u[3] = f32_to_bf16(a[3]);
    o.u[4] = f32_to_bf16(c[0]); o.u[5] = f32_to_bf16(c[1]);
    o.u[6] = f32_to_bf16(c[2]); o.u[7] = f32_to_bf16(c[3]);
    __builtin_nontemporal_store(o.v, (u32x4*)(d + 8 * k));
}

// ---------------- gemm1: 256x256 tile, BK=64, 2-buf drain template ---------
// h[slot] = relu(x_bf[tok[slot]] @ pin_bf^T), K=1024, NT=16
// 8 waves as 2M x 4N: wave -> 128 rows x 64 cols. LDS 2 x 64KB = 128KB.
__global__ __launch_bounds__(THREADS, 2)
void gemm1(const u16* __restrict__ Abase,
           const u16* __restrict__ Bbase,
           const int* __restrict__ meta,
           const int* __restrict__ tok,
           u16* __restrict__ hdst) {
    constexpr int NT = II / 64;       // 16
    constexpr int ASZ = 256 * 64 * 2; // 32768
    constexpr int BUFSZ = 2 * ASZ;    // A + B
    __shared__ char smem[2 * BUFSZ];  // 131072

    const int lid = blockIdx.x;
    const int g = lid & 7;
    const int i = lid >> 3;
    const int tile = g + 8 * (i % 3); // balanced across XCDs when nt<24
    const int colt = i / 3;           // 0..7
    if (tile >= meta[0]) return;

    const int e     = meta[32 + tile];
    const int sbase = meta[64 + tile];
    const int wend  = meta[128 + tile];
    const int padmax = meta[1];
    const int colbase = colt * 256;

    const int tid = threadIdx.x;
    const int lane = tid & 63;
    const int wv = tid >> 6;
    const int wr = wv >> 2;  // 0..1 (128-row stripes)
    const int wc = wv & 3;   // 0..3 (64-col stripes)

    const u16* Bp = Bbase + (size_t)e * (size_t)(DD * II) + (size_t)colbase * II;

    int aoff[4], boff[4], cdst[4];
#pragma unroll
    for (int j = 0; j < 4; j++) {
        int c = j * 512 + tid;
        int row = c >> 3;
        int s = (c & 7) ^ (row & 7);
        cdst[j] = c * 16;
        int slot = sbase + row;
        if (slot > padmax - 1) slot = padmax - 1; // clamp (rows discarded)
        aoff[j] = tok[slot] * II + s * 8;
        boff[j] = row * II + s * 8;
    }

    f32x4 acc[8][4];
#pragma unroll
    for (int m = 0; m < 8; m++)
#pragma unroll
        for (int n = 0; n < 4; n++)
            acc[m][n] = (f32x4){0.f, 0.f, 0.f, 0.f};

    auto STAGE = [&](int kt, char* buf) {
        const int kof = kt * 64;
#pragma unroll
        for (int j = 0; j < 4; j++)
            gload16(Abase + aoff[j] + kof, buf + cdst[j]);
#pragma unroll
        for (int j = 0; j < 4; j++)
            gload16(Bp + boff[j] + kof, buf + ASZ + cdst[j]);
    };

    auto COMPUTE = [&](const char* buf) {
        const u16* As = (const u16*)buf;
        const u16* Bs = (const u16*)(buf + ASZ);
#pragma unroll
        for (int kk = 0; kk < 2; kk++) {
            bf16x8 a[8], b[4];
#pragma unroll
            for (int m = 0; m < 8; m++) {
                int row = wr * 128 + m * 16 + (lane & 15);
                int slot = (kk * 4 + (lane >> 4)) ^ (row & 7);
                a[m] = *(const bf16x8*)&As[row * 64 + slot * 8];
            }
#pragma unroll
            for (int n = 0; n < 4; n++) {
                int col = wc * 64 + n * 16 + (lane & 15);
                int slot = (kk * 4 + (lane >> 4)) ^ (col & 7);
                b[n] = *(const bf16x8*)&Bs[col * 64 + slot * 8];
            }
            asm volatile("s_waitcnt lgkmcnt(0)" ::: "memory");
            __builtin_amdgcn_sched_barrier(0);
            __builtin_amdgcn_s_setprio(1);
#pragma unroll
            for (int m = 0; m < 8; m++)
#pragma unroll
                for (int n = 0; n < 4; n++)
                    acc[m][n] = __builtin_amdgcn_mfma_f32_16x16x32_bf16(
                        a[m], b[n], acc[m][n], 0, 0, 0);
            __builtin_amdgcn_s_setprio(0);
        }
    };

    char* buf0 = smem;
    char* buf1 = smem + BUFSZ;

    STAGE(0, buf0);
    asm volatile("s_waitcnt vmcnt(0)" ::: "memory");
    BARRIER();

#pragma unroll 1
    for (int t = 0; t < NT; ++t) {
        char* cur = (t & 1) ? buf1 : buf0;
        char* nxt = (t & 1) ? buf0 : buf1;
        const bool st = (t + 1 < NT);
        if (st) STAGE(t + 1, nxt);
        COMPUTE(cur);
        if (st) asm volatile("s_waitcnt vmcnt(0)" ::: "memory");
        BARRIER();
    }

#pragma unroll
    for (int m = 0; m < 8; m++) {
#pragma unroll
        for (int r = 0; r < 4; r++) {
            int row = wr * 128 + m * 16 + (lane >> 4) * 4 + r;
            int slot = sbase + row;
            if (slot < wend) { // stay inside this expert's pad region
                size_t ro = (size_t)slot * DD;
#pragma unroll
                for (int n = 0; n < 4; n++) {
                    int col = colbase + wc * 64 + n * 16 + (lane & 15);
                    float v = acc[m][n][r];
                    v = v > 0.f ? v : 0.f;
                    hdst[ro + col] = f32_to_bf16(v);
                }
            }
        }
    }
}

// ---------------- gemm2: 256x128, BK=64, 3-buf counted vmcnt (R10-proven) --
// out[tok[slot]] += wgt * (h[slot] @ pout_bf^T), K=2048, NT=32
__global__ __launch_bounds__(THREADS, 2)
void gemm2(const u16* __restrict__ Abase,
           const u16* __restrict__ Bbase,
           const int* __restrict__ meta,
           const int* __restrict__ tok,
           const float* __restrict__ wgt,
           float* __restrict__ outdst) {
    constexpr int NT = DD / 64;       // 32
    constexpr int ASZ = 256 * 64 * 2; // 32768
    constexpr int BSZ = 128 * 64 * 2; // 16384
    constexpr int BUFSZ = ASZ + BSZ;  // 49152
    __shared__ char smem[3 * BUFSZ];  // 147456

    const int lid = blockIdx.x;
    const int g = lid & 7;
    const int i = lid >> 3;
    const int tile = g + 8 * (i % 3);
    const int colt = i / 3; // 0..7
    if (tile >= meta[0]) return;

    const int e     = meta[32 + tile];
    const int sbase = meta[64 + tile];
    const int rend  = meta[96 + tile];
    const int padmax = meta[1];
    const int colbase = colt * 128;

    const int tid = threadIdx.x;
    const int lane = tid & 63;
    const int wv = tid >> 6;
    const int wr = wv >> 1; // 0..3 (64-row stripes)
    const int wc = wv & 1;  // 0..1 (64-col stripes)

    const u16* Bp = Bbase + (size_t)e * (size_t)(DD * II) + (size_t)colbase * DD;

    int aoff[4], adst[4], boff[2], bdst[2];
#pragma unroll
    for (int j = 0; j < 4; j++) {
        int c = j * 512 + tid;
        int row = c >> 3;
        int s = (c & 7) ^ (row & 7);
        adst[j] = c * 16;
        int slot = sbase + row;
        if (slot > padmax - 1) slot = padmax - 1;
        aoff[j] = slot * DD + s * 8;
    }
#pragma unroll
    for (int j = 0; j < 2; j++) {
        int c = j * 512 + tid;
        int row = c >> 3;
        int s = (c & 7) ^ (row & 7);
        bdst[j] = c * 16;
        boff[j] = row * DD + s * 8;
    }

    f32x4 acc[4][4];
#pragma unroll
    for (int m = 0; m < 4; m++)
#pragma unroll
        for (int n = 0; n < 4; n++)
            acc[m][n] = (f32x4){0.f, 0.f, 0.f, 0.f};

    auto STAGE = [&](int kt, char* buf) {
        const int kof = kt * 64;
#pragma unroll
        for (int j = 0; j < 4; j++)
            gload16(Abase + aoff[j] + kof, buf + adst[j]);
#pragma unroll
        for (int j = 0; j < 2; j++)
            gload16(Bp + boff[j] + kof, buf + ASZ + bdst[j]);
    };

    auto COMPUTE = [&](const char* buf) {
        const u16* As = (const u16*)buf;
        const u16* Bs = (const u16*)(buf + ASZ);
        bf16x8 a[2][4], b[2][4];
#pragma unroll
        for (int kk = 0; kk < 2; kk++) {
#pragma unroll
            for (int m = 0; m < 4; m++) {
                int row = wr * 64 + m * 16 + (lane & 15);
                int slot = (kk * 4 + (lane >> 4)) ^ (row & 7);
                a[kk][m] = *(const bf16x8*)&As[row * 64 + slot * 8];
            }
#pragma unroll
            for (int n = 0; n < 4; n++) {
                int col = wc * 64 + n * 16 + (lane & 15);
                int slot = (kk * 4 + (lane >> 4)) ^ (col & 7);
                b[kk][n] = *(const bf16x8*)&Bs[col * 64 + slot * 8];
            }
        }
        asm volatile("s_waitcnt lgkmcnt(0)" ::: "memory");
        __builtin_amdgcn_sched_barrier(0);
        __builtin_amdgcn_s_setprio(1);
#pragma unroll
        for (int m = 0; m < 4; m++)
#pragma unroll
            for (int n = 0; n < 4; n++) {
                acc[m][n] = __builtin_amdgcn_mfma_f32_16x16x32_bf16(
                    a[0][m], b[0][n], acc[m][n], 0, 0, 0);
                acc[m][n] = __builtin_amdgcn_mfma_f32_16x16x32_bf16(
                    a[1][m], b[1][n], acc[m][n], 0, 0, 0);
            }
        __builtin_amdgcn_s_setprio(0);
    };

    char* pA = smem;
    char* pB = smem + BUFSZ;
    char* pC = smem + 2 * BUFSZ;

    STAGE(0, pA);
    STAGE(1, pB);
    asm volatile("s_waitcnt vmcnt(6)" ::: "memory");
    BARRIER();

#pragma unroll 1
    for (int t = 0; t < NT; ++t) {
        const bool st = (t + 2 < NT);
        if (st) STAGE(t + 2, pC);
        COMPUTE(pA);
        if (st) {
            asm volatile("s_waitcnt vmcnt(6)" ::: "memory"); // retire t+1
        } else if (t + 1 < NT) {
            asm volatile("s_waitcnt vmcnt(0)" ::: "memory"); // tail drain
        }
        BARRIER();
        { char* tp = pA; pA = pB; pB = pC; pC = tp; }
    }

#pragma unroll
    for (int m = 0; m < 4; m++) {
#pragma unroll
        for (int r = 0; r < 4; r++) {
            int row = wr * 64 + m * 16 + (lane >> 4) * 4 + r;
            int slot = sbase + row;
            if (slot < rend) { // skip padding rows
                float w = wgt[slot];
                size_t obase = (size_t)tok[slot] * II;
#pragma unroll
                for (int n = 0; n < 4; n++) {
                    int col = colbase + wc * 64 + n * 16 + (lane & 15);
                    atomicAdd(&outdst[obase + col], acc[m][n][r] * w);
                }
            }
        }
    }
}

// ---------------- launch ----------------
extern "C" void kernel_launch(void* const* d_in, const int* in_sizes, int n_in,
                              void* d_out, int out_size, void* d_ws, size_t ws_size,
                              hipStream_t stream) {
    const float* x = (const float*)d_in[0];
    const float* weights = (const float*)d_in[1];
    const void* ens = d_in[2];
    const float* pin = (const float*)d_in[3];
    const float* pout = (const float*)d_in[4];
    float* out = (float*)d_out;

    char* ws = (char*)d_ws;
    int*   meta    = (int*)(ws);            // 1 KB
    int*   tok     = (int*)(ws + 1024);     // 20 KB
    float* wgt     = (float*)(ws + 21504);  // 20 KB   -> 41984
    u16*   x_bf    = (u16*)(ws + 41984);    // 4 MB    -> 4236288
    u16*   pin_bf  = (u16*)(ws + 4236288);  // 33.5 MB -> 37790720
    u16*   pout_bf = (u16*)(ws + 37790720); // 33.5 MB -> 71345152
    u16*   h       = (u16*)(ws + 71345152); // 21 MB   -> 92316672 total

    setup_kernel<<<dim3(1), dim3(256), 0, stream>>>(ens, weights, meta, tok, wgt);

    hipMemsetAsync(d_out, 0, (size_t)out_size * sizeof(float), stream);

    convert3<<<dim3(CB_TOTAL), dim3(256), 0, stream>>>(
        x, pin, pout, x_bf, pin_bf, pout_bf);

    // gemm1: up to 24 tiles x 8 col-blocks (256-wide), XCD-interleaved
    gemm1<<<dim3(8 * 3 * 8), dim3(THREADS), 0, stream>>>(
        x_bf, pin_bf, meta, tok, h);

    // gemm2: up to 24 tiles x 8 col-blocks (128-wide), 3-buf counted vmcnt
    gemm2<<<dim3(8 * 3 * 8), dim3(THREADS), 0, stream>>>(
        h, pout_bf, meta, tok, wgt, out);
}

// Round 13
// 120.794 us; speedup vs baseline: 1.1784x; 1.1226x over previous
//
#include <hip/hip_runtime.h>
#include <stdint.h>

#define THREADS 512
#define GRID1 (8 * 3 * 8)      // gemm1 fat blocks
#define NE 8
#define BB 4
#define SS 512
#define KK 2
#define II 1024
#define DD 2048
#define NTOK (BB * SS)         // 2048
#define NASSIGN (BB * KK * SS) // 4096

// kernel A convert: x + pin, 1024 f4/block (4 f4/thread, stride 256)
#define F4_X (NTOK * II / 4)     // 524288
#define F4_P (NE * DD * II / 4)  // 4194304
#define CVB_X (F4_X / 1024)      // 512
#define CVB_P (F4_P / 1024)      // 4096
#define CVA_TOTAL (CVB_X + CVB_P) // 4608 (+1 setup)
// hybrid convert: pout, 2048 f4/block (4 f4/thread, stride 512)
#define CVH_P (F4_P / 2048)      // 2048 blocks

typedef unsigned short u16;
typedef __attribute__((ext_vector_type(8))) __bf16 bf16x8;
typedef __attribute__((ext_vector_type(4))) float f32x4;
typedef __attribute__((ext_vector_type(4))) unsigned int u32x4;

__device__ __forceinline__ u16 f32_to_bf16(float f) {
    unsigned int u = __builtin_bit_cast(unsigned int, f);
    unsigned int r = u + 0x7FFFu + ((u >> 16) & 1u);
    return (u16)(r >> 16);
}

__device__ __forceinline__ unsigned int pk2(float a, float b) {
    return (unsigned int)f32_to_bf16(a) | ((unsigned int)f32_to_bf16(b) << 16);
}

__device__ __forceinline__ void gload16(const void* g, void* l) {
    __builtin_amdgcn_global_load_lds(
        (const __attribute__((address_space(1))) unsigned int*)g,
        (__attribute__((address_space(3))) unsigned int*)l, 16, 0, 0);
}

#define BARRIER() do { \
    __builtin_amdgcn_sched_barrier(0); \
    __builtin_amdgcn_s_barrier(); \
    __builtin_amdgcn_sched_barrier(0); } while (0)

// ---------------- setup body (runs as last block of kernel A) --------------
__device__ void setup_body(const void* __restrict__ ens_raw,
                           const float* __restrict__ weights,
                           int* __restrict__ meta,
                           int* __restrict__ tok,
                           float* __restrict__ wgt) {
    __shared__ int s_cnt[NE];
    __shared__ int s_cur[NE];
    __shared__ int s_flag;
    const int t = threadIdx.x;
    if (t < NE) s_cnt[t] = 0;
    if (t == 0) s_flag = 0;
    __syncthreads();

    // dtype detect: int64 ensembles (vals 0..7) -> all odd 32-bit words zero
    const unsigned int* w32 = (const unsigned int*)ens_raw;
    unsigned int f = 0;
    for (int i = t; i < NASSIGN / 2; i += 256) f |= w32[2 * i + 1];
    if (f) atomicOr(&s_flag, 1);
    __syncthreads();
    const bool is32 = (s_flag != 0);
    const int* e32 = (const int*)ens_raw;
    const long long* e64 = (const long long*)ens_raw;

    for (int a = t; a < NASSIGN; a += 256) {
        int e = is32 ? e32[a] : (int)e64[a];
        atomicAdd(&s_cnt[e & 7], 1);
    }
    __syncthreads();

    if (t == 0) {
        int pb = 0, nt = 0;
        for (int e = 0; e < NE; e++) {
            int c = s_cnt[e];
            meta[8 + e] = c;
            meta[16 + e] = pb;
            s_cur[e] = pb;
            int n128 = (c + 127) >> 7;
            int pe = pb + n128 * 128;
            for (int i2 = 0; i2 < n128; i2 += 2) {
                meta[32 + nt] = e;             // expert
                meta[64 + nt] = pb + i2 * 128; // slot base (256-row tile)
                meta[96 + nt] = pb + c;        // real end (atomic guard)
                meta[128 + nt] = pe;           // pad end  (h-write guard)
                nt++;
            }
            pb = pe;
        }
        meta[0] = nt;
        meta[1] = pb;
    }
    __syncthreads();

    for (int a = t; a < NASSIGN; a += 256) {
        int e = is32 ? e32[a] : (int)e64[a];
        e &= 7;
        int slot = atomicAdd(&s_cur[e], 1);
        int b = a >> 10;
        int s = a & (SS - 1);
        tok[slot] = b * SS + s;
        wgt[slot] = weights[a];
    }
    __syncthreads();

    // pad fill
    for (int e = 0; e < NE; e++) {
        int st = meta[16 + e] + meta[8 + e];
        int en = (e < NE - 1) ? meta[16 + e + 1] : meta[1];
        for (int i = st + t; i < en; i += 256) {
            tok[i] = 0;
            wgt[i] = 0.f;
        }
    }
}

// ---------------- kernel A: convert x + pin (R10 pattern) + setup ----------
__global__ __launch_bounds__(256)
void convert_setup(const float* __restrict__ x,
                   const float* __restrict__ pin,
                   u16* __restrict__ xb,
                   u16* __restrict__ pb1,
                   const void* __restrict__ ens,
                   const float* __restrict__ weights,
                   int* __restrict__ meta,
                   int* __restrict__ tok,
                   float* __restrict__ wgt) {
    const int b = blockIdx.x;
    if (b >= CVA_TOTAL) {
        setup_body(ens, weights, meta, tok, wgt);
        return;
    }
    const float* s;
    u16* d;
    size_t base;
    if (b < CVB_X) { s = x;   d = xb;  base = (size_t)b * 1024; }
    else           { s = pin; d = pb1; base = (size_t)(b - CVB_X) * 1024; }
    const f32x4* s4 = (const f32x4*)s;
    f32x4 v[4];
#pragma unroll
    for (int q = 0; q < 4; q++)
        v[q] = __builtin_nontemporal_load(&s4[base + q * 256 + threadIdx.x]);
#pragma unroll
    for (int q = 0; q < 4; q++) {
        uint2 o;
        o.x = pk2(v[q][0], v[q][1]);
        o.y = pk2(v[q][2], v[q][3]);
        *(uint2*)(d + 4 * (base + q * 256 + threadIdx.x)) = o;
    }
}

// ---------------- gemm1 hybrid: 256x256 tile 2-buf drain + pout convert ----
// lid <  GRID1: h[slot] = relu(x_bf[tok[slot]] @ pin_bf^T), K=1024, NT=16
// lid >= GRID1: convert a 2048-f4 slice of pout -> pout_bf (fills idle CUs)
__global__ __launch_bounds__(THREADS, 2)
void gemm1(const u16* __restrict__ Abase,
           const u16* __restrict__ Bbase,
           const int* __restrict__ meta,
           const int* __restrict__ tok,
           u16* __restrict__ hdst,
           const float* __restrict__ pout,
           u16* __restrict__ pout_bf) {
    constexpr int NT = II / 64;       // 16
    constexpr int ASZ = 256 * 64 * 2; // 32768
    constexpr int BUFSZ = 2 * ASZ;    // A + B
    __shared__ char smem[2 * BUFSZ];  // 131072

    const int lid = blockIdx.x;
    if (lid >= GRID1) {
        // ---- pout conversion block: 4 f4/thread, stride 512 ----
        const size_t base = (size_t)(lid - GRID1) * 2048;
        const f32x4* s4 = (const f32x4*)pout;
        f32x4 v[4];
#pragma unroll
        for (int q = 0; q < 4; q++)
            v[q] = __builtin_nontemporal_load(&s4[base + q * 512 + threadIdx.x]);
#pragma unroll
        for (int q = 0; q < 4; q++) {
            uint2 o;
            o.x = pk2(v[q][0], v[q][1]);
            o.y = pk2(v[q][2], v[q][3]);
            *(uint2*)(pout_bf + 4 * (base + q * 512 + threadIdx.x)) = o;
        }
        return;
    }

    const int g = lid & 7;
    const int i = lid >> 3;
    const int tile = g + 8 * (i % 3); // balanced across XCDs when nt<24
    const int colt = i / 3;           // 0..7
    if (tile >= meta[0]) return;

    const int e     = meta[32 + tile];
    const int sbase = meta[64 + tile];
    const int wend  = meta[128 + tile];
    const int padmax = meta[1];
    const int colbase = colt * 256;

    const int tid = threadIdx.x;
    const int lane = tid & 63;
    const int wv = tid >> 6;
    const int wr = wv >> 2;  // 0..1 (128-row stripes)
    const int wc = wv & 3;   // 0..3 (64-col stripes)

    const u16* Bp = Bbase + (size_t)e * (size_t)(DD * II) + (size_t)colbase * II;

    int aoff[4], boff[4], cdst[4];
#pragma unroll
    for (int j = 0; j < 4; j++) {
        int c = j * 512 + tid;
        int row = c >> 3;
        int s = (c & 7) ^ (row & 7);
        cdst[j] = c * 16;
        int slot = sbase + row;
        if (slot > padmax - 1) slot = padmax - 1; // clamp (rows discarded)
        aoff[j] = tok[slot] * II + s * 8;
        boff[j] = row * II + s * 8;
    }

    f32x4 acc[8][4];
#pragma unroll
    for (int m = 0; m < 8; m++)
#pragma unroll
        for (int n = 0; n < 4; n++)
            acc[m][n] = (f32x4){0.f, 0.f, 0.f, 0.f};

    auto STAGE = [&](int kt, char* buf) {
        const int kof = kt * 64;
#pragma unroll
        for (int j = 0; j < 4; j++)
            gload16(Abase + aoff[j] + kof, buf + cdst[j]);
#pragma unroll
        for (int j = 0; j < 4; j++)
            gload16(Bp + boff[j] + kof, buf + ASZ + cdst[j]);
    };

    auto COMPUTE = [&](const char* buf) {
        const u16* As = (const u16*)buf;
        const u16* Bs = (const u16*)(buf + ASZ);
#pragma unroll
        for (int kk = 0; kk < 2; kk++) {
            bf16x8 a[8], b[4];
#pragma unroll
            for (int m = 0; m < 8; m++) {
                int row = wr * 128 + m * 16 + (lane & 15);
                int slot = (kk * 4 + (lane >> 4)) ^ (row & 7);
                a[m] = *(const bf16x8*)&As[row * 64 + slot * 8];
            }
#pragma unroll
            for (int n = 0; n < 4; n++) {
                int col = wc * 64 + n * 16 + (lane & 15);
                int slot = (kk * 4 + (lane >> 4)) ^ (col & 7);
                b[n] = *(const bf16x8*)&Bs[col * 64 + slot * 8];
            }
            asm volatile("s_waitcnt lgkmcnt(0)" ::: "memory");
            __builtin_amdgcn_sched_barrier(0);
            __builtin_amdgcn_s_setprio(1);
#pragma unroll
            for (int m = 0; m < 8; m++)
#pragma unroll
                for (int n = 0; n < 4; n++)
                    acc[m][n] = __builtin_amdgcn_mfma_f32_16x16x32_bf16(
                        a[m], b[n], acc[m][n], 0, 0, 0);
            __builtin_amdgcn_s_setprio(0);
        }
    };

    char* buf0 = smem;
    char* buf1 = smem + BUFSZ;

    STAGE(0, buf0);
    asm volatile("s_waitcnt vmcnt(0)" ::: "memory");
    BARRIER();

#pragma unroll 1
    for (int t = 0; t < NT; ++t) {
        char* cur = (t & 1) ? buf1 : buf0;
        char* nxt = (t & 1) ? buf0 : buf1;
        const bool st = (t + 1 < NT);
        if (st) STAGE(t + 1, nxt);
        COMPUTE(cur);
        if (st) asm volatile("s_waitcnt vmcnt(0)" ::: "memory");
        BARRIER();
    }

#pragma unroll
    for (int m = 0; m < 8; m++) {
#pragma unroll
        for (int r = 0; r < 4; r++) {
            int row = wr * 128 + m * 16 + (lane >> 4) * 4 + r;
            int slot = sbase + row;
            if (slot < wend) { // stay inside this expert's pad region
                size_t ro = (size_t)slot * DD;
#pragma unroll
                for (int n = 0; n < 4; n++) {
                    int col = colbase + wc * 64 + n * 16 + (lane & 15);
                    float v = acc[m][n][r];
                    v = v > 0.f ? v : 0.f;
                    hdst[ro + col] = f32_to_bf16(v);
                }
            }
        }
    }
}

// ---------------- gemm2: 256x128, BK=64, 3-buf counted vmcnt (R10-proven) --
// out[tok[slot]] += wgt * (h[slot] @ pout_bf^T), K=2048, NT=32
__global__ __launch_bounds__(THREADS, 2)
void gemm2(const u16* __restrict__ Abase,
           const u16* __restrict__ Bbase,
           const int* __restrict__ meta,
           const int* __restrict__ tok,
           const float* __restrict__ wgt,
           float* __restrict__ outdst) {
    constexpr int NT = DD / 64;       // 32
    constexpr int ASZ = 256 * 64 * 2; // 32768
    constexpr int BSZ = 128 * 64 * 2; // 16384
    constexpr int BUFSZ = ASZ + BSZ;  // 49152
    __shared__ char smem[3 * BUFSZ];  // 147456

    const int lid = blockIdx.x;
    const int g = lid & 7;
    const int i = lid >> 3;
    const int tile = g + 8 * (i % 3);
    const int colt = i / 3; // 0..7
    if (tile >= meta[0]) return;

    const int e     = meta[32 + tile];
    const int sbase = meta[64 + tile];
    const int rend  = meta[96 + tile];
    const int padmax = meta[1];
    const int colbase = colt * 128;

    const int tid = threadIdx.x;
    const int lane = tid & 63;
    const int wv = tid >> 6;
    const int wr = wv >> 1; // 0..3 (64-row stripes)
    const int wc = wv & 1;  // 0..1 (64-col stripes)

    const u16* Bp = Bbase + (size_t)e * (size_t)(DD * II) + (size_t)colbase * DD;

    int aoff[4], adst[4], boff[2], bdst[2];
#pragma unroll
    for (int j = 0; j < 4; j++) {
        int c = j * 512 + tid;
        int row = c >> 3;
        int s = (c & 7) ^ (row & 7);
        adst[j] = c * 16;
        int slot = sbase + row;
        if (slot > padmax - 1) slot = padmax - 1;
        aoff[j] = slot * DD + s * 8;
    }
#pragma unroll
    for (int j = 0; j < 2; j++) {
        int c = j * 512 + tid;
        int row = c >> 3;
        int s = (c & 7) ^ (row & 7);
        bdst[j] = c * 16;
        boff[j] = row * DD + s * 8;
    }

    f32x4 acc[4][4];
#pragma unroll
    for (int m = 0; m < 4; m++)
#pragma unroll
        for (int n = 0; n < 4; n++)
            acc[m][n] = (f32x4){0.f, 0.f, 0.f, 0.f};

    auto STAGE = [&](int kt, char* buf) {
        const int kof = kt * 64;
#pragma unroll
        for (int j = 0; j < 4; j++)
            gload16(Abase + aoff[j] + kof, buf + adst[j]);
#pragma unroll
        for (int j = 0; j < 2; j++)
            gload16(Bp + boff[j] + kof, buf + ASZ + bdst[j]);
    };

    auto COMPUTE = [&](const char* buf) {
        const u16* As = (const u16*)buf;
        const u16* Bs = (const u16*)(buf + ASZ);
        bf16x8 a[2][4], b[2][4];
#pragma unroll
        for (int kk = 0; kk < 2; kk++) {
#pragma unroll
            for (int m = 0; m < 4; m++) {
                int row = wr * 64 + m * 16 + (lane & 15);
                int slot = (kk * 4 + (lane >> 4)) ^ (row & 7);
                a[kk][m] = *(const bf16x8*)&As[row * 64 + slot * 8];
            }
#pragma unroll
            for (int n = 0; n < 4; n++) {
                int col = wc * 64 + n * 16 + (lane & 15);
                int slot = (kk * 4 + (lane >> 4)) ^ (col & 7);
                b[kk][n] = *(const bf16x8*)&Bs[col * 64 + slot * 8];
            }
        }
        asm volatile("s_waitcnt lgkmcnt(0)" ::: "memory");
        __builtin_amdgcn_sched_barrier(0);
        __builtin_amdgcn_s_setprio(1);
#pragma unroll
        for (int m = 0; m < 4; m++)
#pragma unroll
            for (int n = 0; n < 4; n++) {
                acc[m][n] = __builtin_amdgcn_mfma_f32_16x16x32_bf16(
                    a[0][m], b[0][n], acc[m][n], 0, 0, 0);
                acc[m][n] = __builtin_amdgcn_mfma_f32_16x16x32_bf16(
                    a[1][m], b[1][n], acc[m][n], 0, 0, 0);
            }
        __builtin_amdgcn_s_setprio(0);
    };

    char* pA = smem;
    char* pB = smem + BUFSZ;
    char* pC = smem + 2 * BUFSZ;

    STAGE(0, pA);
    STAGE(1, pB);
    asm volatile("s_waitcnt vmcnt(6)" ::: "memory");
    BARRIER();

#pragma unroll 1
    for (int t = 0; t < NT; ++t) {
        const bool st = (t + 2 < NT);
        if (st) STAGE(t + 2, pC);
        COMPUTE(pA);
        if (st) {
            asm volatile("s_waitcnt vmcnt(6)" ::: "memory"); // retire t+1
        } else if (t + 1 < NT) {
            asm volatile("s_waitcnt vmcnt(0)" ::: "memory"); // tail drain
        }
        BARRIER();
        { char* tp = pA; pA = pB; pB = pC; pC = tp; }
    }

#pragma unroll
    for (int m = 0; m < 4; m++) {
#pragma unroll
        for (int r = 0; r < 4; r++) {
            int row = wr * 64 + m * 16 + (lane >> 4) * 4 + r;
            int slot = sbase + row;
            if (slot < rend) { // skip padding rows
                float w = wgt[slot];
                size_t obase = (size_t)tok[slot] * II;
#pragma unroll
                for (int n = 0; n < 4; n++) {
                    int col = colbase + wc * 64 + n * 16 + (lane & 15);
                    atomicAdd(&outdst[obase + col], acc[m][n][r] * w);
                }
            }
        }
    }
}

// ---------------- launch ----------------
extern "C" void kernel_launch(void* const* d_in, const int* in_sizes, int n_in,
                              void* d_out, int out_size, void* d_ws, size_t ws_size,
                              hipStream_t stream) {
    const float* x = (const float*)d_in[0];
    const float* weights = (const float*)d_in[1];
    const void* ens = d_in[2];
    const float* pin = (const float*)d_in[3];
    const float* pout = (const float*)d_in[4];
    float* out = (float*)d_out;

    char* ws = (char*)d_ws;
    int*   meta    = (int*)(ws);            // 1 KB
    int*   tok     = (int*)(ws + 1024);     // 20 KB
    float* wgt     = (float*)(ws + 21504);  // 20 KB   -> 41984
    u16*   x_bf    = (u16*)(ws + 41984);    // 4 MB    -> 4236288
    u16*   pin_bf  = (u16*)(ws + 4236288);  // 33.5 MB -> 37790720
    u16*   pout_bf = (u16*)(ws + 37790720); // 33.5 MB -> 71345152
    u16*   h       = (u16*)(ws + 71345152); // 21 MB   -> 92316672 total

    hipMemsetAsync(d_out, 0, (size_t)out_size * sizeof(float), stream);

    // A: convert x + pin; last block buckets assignments
    convert_setup<<<dim3(CVA_TOTAL + 1), dim3(256), 0, stream>>>(
        x, pin, x_bf, pin_bf, ens, weights, meta, tok, wgt);

    // B: gemm1 (192 fat blocks) + pout conversion (2048 light blocks)
    gemm1<<<dim3(GRID1 + CVH_P), dim3(THREADS), 0, stream>>>(
        x_bf, pin_bf, meta, tok, h, pout, pout_bf);

    // C: gemm2 (unchanged)
    gemm2<<<dim3(8 * 3 * 8), dim3(THREADS), 0, stream>>>(
        h, pout_bf, meta, tok, wgt, out);
}

// Round 14
// 111.864 us; speedup vs baseline: 1.2725x; 1.0798x over previous
//
#include <hip/hip_runtime.h>
#include <stdint.h>

#define THREADS 512
#define GRID1 (8 * 3 * 8)      // gemm1 fat blocks
#define NE 8
#define BB 4
#define SS 512
#define KK 2
#define II 1024
#define DD 2048
#define NTOK (BB * SS)         // 2048
#define NASSIGN (BB * KK * SS) // 4096

// kernel A convert: x + pin, 1024 f4/block (4 f4/thread, stride 256)
#define F4_X (NTOK * II / 4)     // 524288
#define F4_P (NE * DD * II / 4)  // 4194304
#define CVB_X (F4_X / 1024)      // 512
#define CVB_P (F4_P / 1024)      // 4096
#define CVA_TOTAL (CVB_X + CVB_P) // 4608 (+1 setup)
// hybrid convert: pout, 2048 f4/block (4 f4/thread, stride 512)
#define CVH_P (F4_P / 2048)      // 2048 blocks

typedef unsigned short u16;
typedef __attribute__((ext_vector_type(8))) __bf16 bf16x8;
typedef __attribute__((ext_vector_type(4))) float f32x4;
typedef __attribute__((ext_vector_type(4))) unsigned int u32x4;

__device__ __forceinline__ u16 f32_to_bf16(float f) {
    unsigned int u = __builtin_bit_cast(unsigned int, f);
    unsigned int r = u + 0x7FFFu + ((u >> 16) & 1u);
    return (u16)(r >> 16);
}

__device__ __forceinline__ unsigned int pk2(float a, float b) {
    return (unsigned int)f32_to_bf16(a) | ((unsigned int)f32_to_bf16(b) << 16);
}

__device__ __forceinline__ void gload16(const void* g, void* l) {
    __builtin_amdgcn_global_load_lds(
        (const __attribute__((address_space(1))) unsigned int*)g,
        (__attribute__((address_space(3))) unsigned int*)l, 16, 0, 0);
}

#define BARRIER() do { \
    __builtin_amdgcn_sched_barrier(0); \
    __builtin_amdgcn_s_barrier(); \
    __builtin_amdgcn_sched_barrier(0); } while (0)

// ---------------- setup body (runs as last block of kernel A) --------------
__device__ void setup_body(const void* __restrict__ ens_raw,
                           const float* __restrict__ weights,
                           int* __restrict__ meta,
                           int* __restrict__ tok,
                           float* __restrict__ wgt,
                           int* __restrict__ inv) {
    __shared__ int s_cnt[NE];
    __shared__ int s_cur[NE];
    __shared__ int s_flag;
    const int t = threadIdx.x;
    if (t < NE) s_cnt[t] = 0;
    if (t == 0) s_flag = 0;
    __syncthreads();

    // dtype detect: int64 ensembles (vals 0..7) -> all odd 32-bit words zero
    const unsigned int* w32 = (const unsigned int*)ens_raw;
    unsigned int f = 0;
    for (int i = t; i < NASSIGN / 2; i += 256) f |= w32[2 * i + 1];
    if (f) atomicOr(&s_flag, 1);
    __syncthreads();
    const bool is32 = (s_flag != 0);
    const int* e32 = (const int*)ens_raw;
    const long long* e64 = (const long long*)ens_raw;

    for (int a = t; a < NASSIGN; a += 256) {
        int e = is32 ? e32[a] : (int)e64[a];
        atomicAdd(&s_cnt[e & 7], 1);
    }
    __syncthreads();

    if (t == 0) {
        int pb = 0, nt = 0;
        for (int e = 0; e < NE; e++) {
            int c = s_cnt[e];
            meta[8 + e] = c;
            meta[16 + e] = pb;
            s_cur[e] = pb;
            int n128 = (c + 127) >> 7;
            int pe = pb + n128 * 128;
            for (int i2 = 0; i2 < n128; i2 += 2) {
                meta[32 + nt] = e;             // expert
                meta[64 + nt] = pb + i2 * 128; // slot base (256-row tile)
                meta[96 + nt] = pb + c;        // real end (store guard)
                meta[128 + nt] = pe;           // pad end  (h-write guard)
                nt++;
            }
            pb = pe;
        }
        meta[0] = nt;
        meta[1] = pb;
    }
    __syncthreads();

    for (int a = t; a < NASSIGN; a += 256) {
        int e = is32 ? e32[a] : (int)e64[a];
        e &= 7;
        int slot = atomicAdd(&s_cur[e], 1);
        int b = a >> 10;          // a = (b*KK + k)*SS + s
        int k = (a >> 9) & 1;
        int s = a & (SS - 1);
        int token = b * SS + s;
        tok[slot] = token;
        wgt[slot] = weights[a];
        inv[token * 2 + k] = slot; // inverse map for the reduce pass
    }
    __syncthreads();

    // pad fill
    for (int e = 0; e < NE; e++) {
        int st = meta[16 + e] + meta[8 + e];
        int en = (e < NE - 1) ? meta[16 + e + 1] : meta[1];
        for (int i = st + t; i < en; i += 256) {
            tok[i] = 0;
            wgt[i] = 0.f;
        }
    }
}

// ---------------- kernel A: convert x + pin + setup ------------------------
__global__ __launch_bounds__(256)
void convert_setup(const float* __restrict__ x,
                   const float* __restrict__ pin,
                   u16* __restrict__ xb,
                   u16* __restrict__ pb1,
                   const void* __restrict__ ens,
                   const float* __restrict__ weights,
                   int* __restrict__ meta,
                   int* __restrict__ tok,
                   float* __restrict__ wgt,
                   int* __restrict__ inv) {
    const int b = blockIdx.x;
    if (b >= CVA_TOTAL) {
        setup_body(ens, weights, meta, tok, wgt, inv);
        return;
    }
    const float* s;
    u16* d;
    size_t base;
    if (b < CVB_X) { s = x;   d = xb;  base = (size_t)b * 1024; }
    else           { s = pin; d = pb1; base = (size_t)(b - CVB_X) * 1024; }
    const f32x4* s4 = (const f32x4*)s;
    f32x4 v[4];
#pragma unroll
    for (int q = 0; q < 4; q++)
        v[q] = __builtin_nontemporal_load(&s4[base + q * 256 + threadIdx.x]);
#pragma unroll
    for (int q = 0; q < 4; q++) {
        uint2 o;
        o.x = pk2(v[q][0], v[q][1]);
        o.y = pk2(v[q][2], v[q][3]);
        *(uint2*)(d + 4 * (base + q * 256 + threadIdx.x)) = o;
    }
}

// ---------------- gemm1 hybrid: 256x256 tile 2-buf drain + pout convert ----
// lid <  GRID1: h[slot] = relu(x_bf[tok[slot]] @ pin_bf^T), K=1024, NT=16
// lid >= GRID1: convert a 2048-f4 slice of pout -> pout_bf (fills idle CUs)
__global__ __launch_bounds__(THREADS, 2)
void gemm1(const u16* __restrict__ Abase,
           const u16* __restrict__ Bbase,
           const int* __restrict__ meta,
           const int* __restrict__ tok,
           u16* __restrict__ hdst,
           const float* __restrict__ pout,
           u16* __restrict__ pout_bf) {
    constexpr int NT = II / 64;       // 16
    constexpr int ASZ = 256 * 64 * 2; // 32768
    constexpr int BUFSZ = 2 * ASZ;    // A + B
    __shared__ char smem[2 * BUFSZ];  // 131072

    const int lid = blockIdx.x;
    if (lid >= GRID1) {
        // ---- pout conversion block: 4 f4/thread, stride 512 ----
        const size_t base = (size_t)(lid - GRID1) * 2048;
        const f32x4* s4 = (const f32x4*)pout;
        f32x4 v[4];
#pragma unroll
        for (int q = 0; q < 4; q++)
            v[q] = __builtin_nontemporal_load(&s4[base + q * 512 + threadIdx.x]);
#pragma unroll
        for (int q = 0; q < 4; q++) {
            uint2 o;
            o.x = pk2(v[q][0], v[q][1]);
            o.y = pk2(v[q][2], v[q][3]);
            *(uint2*)(pout_bf + 4 * (base + q * 512 + threadIdx.x)) = o;
        }
        return;
    }

    const int g = lid & 7;
    const int i = lid >> 3;
    const int tile = g + 8 * (i % 3); // balanced across XCDs when nt<24
    const int colt = i / 3;           // 0..7
    if (tile >= meta[0]) return;

    const int e     = meta[32 + tile];
    const int sbase = meta[64 + tile];
    const int wend  = meta[128 + tile];
    const int padmax = meta[1];
    const int colbase = colt * 256;

    const int tid = threadIdx.x;
    const int lane = tid & 63;
    const int wv = tid >> 6;
    const int wr = wv >> 2;  // 0..1 (128-row stripes)
    const int wc = wv & 3;   // 0..3 (64-col stripes)

    const u16* Bp = Bbase + (size_t)e * (size_t)(DD * II) + (size_t)colbase * II;

    int aoff[4], boff[4], cdst[4];
#pragma unroll
    for (int j = 0; j < 4; j++) {
        int c = j * 512 + tid;
        int row = c >> 3;
        int s = (c & 7) ^ (row & 7);
        cdst[j] = c * 16;
        int slot = sbase + row;
        if (slot > padmax - 1) slot = padmax - 1; // clamp (rows discarded)
        aoff[j] = tok[slot] * II + s * 8;
        boff[j] = row * II + s * 8;
    }

    f32x4 acc[8][4];
#pragma unroll
    for (int m = 0; m < 8; m++)
#pragma unroll
        for (int n = 0; n < 4; n++)
            acc[m][n] = (f32x4){0.f, 0.f, 0.f, 0.f};

    auto STAGE = [&](int kt, char* buf) {
        const int kof = kt * 64;
#pragma unroll
        for (int j = 0; j < 4; j++)
            gload16(Abase + aoff[j] + kof, buf + cdst[j]);
#pragma unroll
        for (int j = 0; j < 4; j++)
            gload16(Bp + boff[j] + kof, buf + ASZ + cdst[j]);
    };

    auto COMPUTE = [&](const char* buf) {
        const u16* As = (const u16*)buf;
        const u16* Bs = (const u16*)(buf + ASZ);
#pragma unroll
        for (int kk = 0; kk < 2; kk++) {
            bf16x8 a[8], b[4];
#pragma unroll
            for (int m = 0; m < 8; m++) {
                int row = wr * 128 + m * 16 + (lane & 15);
                int slot = (kk * 4 + (lane >> 4)) ^ (row & 7);
                a[m] = *(const bf16x8*)&As[row * 64 + slot * 8];
            }
#pragma unroll
            for (int n = 0; n < 4; n++) {
                int col = wc * 64 + n * 16 + (lane & 15);
                int slot = (kk * 4 + (lane >> 4)) ^ (col & 7);
                b[n] = *(const bf16x8*)&Bs[col * 64 + slot * 8];
            }
            asm volatile("s_waitcnt lgkmcnt(0)" ::: "memory");
            __builtin_amdgcn_sched_barrier(0);
            __builtin_amdgcn_s_setprio(1);
#pragma unroll
            for (int m = 0; m < 8; m++)
#pragma unroll
                for (int n = 0; n < 4; n++)
                    acc[m][n] = __builtin_amdgcn_mfma_f32_16x16x32_bf16(
                        a[m], b[n], acc[m][n], 0, 0, 0);
            __builtin_amdgcn_s_setprio(0);
        }
    };

    char* buf0 = smem;
    char* buf1 = smem + BUFSZ;

    STAGE(0, buf0);
    asm volatile("s_waitcnt vmcnt(0)" ::: "memory");
    BARRIER();

#pragma unroll 1
    for (int t = 0; t < NT; ++t) {
        char* cur = (t & 1) ? buf1 : buf0;
        char* nxt = (t & 1) ? buf0 : buf1;
        const bool st = (t + 1 < NT);
        if (st) STAGE(t + 1, nxt);
        COMPUTE(cur);
        if (st) asm volatile("s_waitcnt vmcnt(0)" ::: "memory");
        BARRIER();
    }

#pragma unroll
    for (int m = 0; m < 8; m++) {
#pragma unroll
        for (int r = 0; r < 4; r++) {
            int row = wr * 128 + m * 16 + (lane >> 4) * 4 + r;
            int slot = sbase + row;
            if (slot < wend) { // stay inside this expert's pad region
                size_t ro = (size_t)slot * DD;
#pragma unroll
                for (int n = 0; n < 4; n++) {
                    int col = colbase + wc * 64 + n * 16 + (lane & 15);
                    float v = acc[m][n][r];
                    v = v > 0.f ? v : 0.f;
                    hdst[ro + col] = f32_to_bf16(v);
                }
            }
        }
    }
}

// ---------------- gemm2: 256x128, BK=64, 3-buf counted vmcnt ---------------
// o_slot[slot] = h[slot] @ pout_bf^T  (plain nontemporal stores, no atomics)
__global__ __launch_bounds__(THREADS, 2)
void gemm2(const u16* __restrict__ Abase,
           const u16* __restrict__ Bbase,
           const int* __restrict__ meta,
           float* __restrict__ o_slot) {
    constexpr int NT = DD / 64;       // 32
    constexpr int ASZ = 256 * 64 * 2; // 32768
    constexpr int BSZ = 128 * 64 * 2; // 16384
    constexpr int BUFSZ = ASZ + BSZ;  // 49152
    __shared__ char smem[3 * BUFSZ];  // 147456

    const int lid = blockIdx.x;
    const int g = lid & 7;
    const int i = lid >> 3;
    const int tile = g + 8 * (i % 3);
    const int colt = i / 3; // 0..7
    if (tile >= meta[0]) return;

    const int e     = meta[32 + tile];
    const int sbase = meta[64 + tile];
    const int rend  = meta[96 + tile];
    const int padmax = meta[1];
    const int colbase = colt * 128;

    const int tid = threadIdx.x;
    const int lane = tid & 63;
    const int wv = tid >> 6;
    const int wr = wv >> 1; // 0..3 (64-row stripes)
    const int wc = wv & 1;  // 0..1 (64-col stripes)

    const u16* Bp = Bbase + (size_t)e * (size_t)(DD * II) + (size_t)colbase * DD;

    int aoff[4], adst[4], boff[2], bdst[2];
#pragma unroll
    for (int j = 0; j < 4; j++) {
        int c = j * 512 + tid;
        int row = c >> 3;
        int s = (c & 7) ^ (row & 7);
        adst[j] = c * 16;
        int slot = sbase + row;
        if (slot > padmax - 1) slot = padmax - 1;
        aoff[j] = slot * DD + s * 8;
    }
#pragma unroll
    for (int j = 0; j < 2; j++) {
        int c = j * 512 + tid;
        int row = c >> 3;
        int s = (c & 7) ^ (row & 7);
        bdst[j] = c * 16;
        boff[j] = row * DD + s * 8;
    }

    f32x4 acc[4][4];
#pragma unroll
    for (int m = 0; m < 4; m++)
#pragma unroll
        for (int n = 0; n < 4; n++)
            acc[m][n] = (f32x4){0.f, 0.f, 0.f, 0.f};

    auto STAGE = [&](int kt, char* buf) {
        const int kof = kt * 64;
#pragma unroll
        for (int j = 0; j < 4; j++)
            gload16(Abase + aoff[j] + kof, buf + adst[j]);
#pragma unroll
        for (int j = 0; j < 2; j++)
            gload16(Bp + boff[j] + kof, buf + ASZ + bdst[j]);
    };

    auto COMPUTE = [&](const char* buf) {
        const u16* As = (const u16*)buf;
        const u16* Bs = (const u16*)(buf + ASZ);
        bf16x8 a[2][4], b[2][4];
#pragma unroll
        for (int kk = 0; kk < 2; kk++) {
#pragma unroll
            for (int m = 0; m < 4; m++) {
                int row = wr * 64 + m * 16 + (lane & 15);
                int slot = (kk * 4 + (lane >> 4)) ^ (row & 7);
                a[kk][m] = *(const bf16x8*)&As[row * 64 + slot * 8];
            }
#pragma unroll
            for (int n = 0; n < 4; n++) {
                int col = wc * 64 + n * 16 + (lane & 15);
                int slot = (kk * 4 + (lane >> 4)) ^ (col & 7);
                b[kk][n] = *(const bf16x8*)&Bs[col * 64 + slot * 8];
            }
        }
        asm volatile("s_waitcnt lgkmcnt(0)" ::: "memory");
        __builtin_amdgcn_sched_barrier(0);
        __builtin_amdgcn_s_setprio(1);
#pragma unroll
        for (int m = 0; m < 4; m++)
#pragma unroll
            for (int n = 0; n < 4; n++) {
                acc[m][n] = __builtin_amdgcn_mfma_f32_16x16x32_bf16(
                    a[0][m], b[0][n], acc[m][n], 0, 0, 0);
                acc[m][n] = __builtin_amdgcn_mfma_f32_16x16x32_bf16(
                    a[1][m], b[1][n], acc[m][n], 0, 0, 0);
            }
        __builtin_amdgcn_s_setprio(0);
    };

    char* pA = smem;
    char* pB = smem + BUFSZ;
    char* pC = smem + 2 * BUFSZ;

    STAGE(0, pA);
    STAGE(1, pB);
    asm volatile("s_waitcnt vmcnt(6)" ::: "memory");
    BARRIER();

#pragma unroll 1
    for (int t = 0; t < NT; ++t) {
        const bool st = (t + 2 < NT);
        if (st) STAGE(t + 2, pC);
        COMPUTE(pA);
        if (st) {
            asm volatile("s_waitcnt vmcnt(6)" ::: "memory"); // retire t+1
        } else if (t + 1 < NT) {
            asm volatile("s_waitcnt vmcnt(0)" ::: "memory"); // tail drain
        }
        BARRIER();
        { char* tp = pA; pA = pB; pB = pC; pC = tp; }
    }

#pragma unroll
    for (int m = 0; m < 4; m++) {
#pragma unroll
        for (int r = 0; r < 4; r++) {
            int row = wr * 64 + m * 16 + (lane >> 4) * 4 + r;
            int slot = sbase + row;
            if (slot < rend) { // skip padding rows
                float* orow = o_slot + (size_t)slot * II + colbase;
#pragma unroll
                for (int n = 0; n < 4; n++) {
                    int col = wc * 64 + n * 16 + (lane & 15);
                    __builtin_nontemporal_store(acc[m][n][r], orow + col);
                }
            }
        }
    }
}

// ---------------- reduce: out[t] = w0*o_slot[s0] + w1*o_slot[s1] -----------
__global__ __launch_bounds__(256)
void reduce_out(const float* __restrict__ o_slot,
                const int* __restrict__ inv,
                const float* __restrict__ wgt,
                float* __restrict__ out) {
    const int t = blockIdx.x;          // token
    const int s0 = inv[2 * t];
    const int s1 = inv[2 * t + 1];
    const float w0 = wgt[s0];
    const float w1 = wgt[s1];
    const f32x4* r0 = (const f32x4*)(o_slot + (size_t)s0 * II);
    const f32x4* r1 = (const f32x4*)(o_slot + (size_t)s1 * II);
    f32x4* o = (f32x4*)(out + (size_t)t * II);
    const int c = threadIdx.x; // 256 threads x f32x4 = 1024 floats
    f32x4 a = r0[c];
    f32x4 b = r1[c];
    f32x4 v;
#pragma unroll
    for (int j = 0; j < 4; j++) v[j] = w0 * a[j] + w1 * b[j];
    __builtin_nontemporal_store(v, &o[c]);
}

// ---------------- launch ----------------
extern "C" void kernel_launch(void* const* d_in, const int* in_sizes, int n_in,
                              void* d_out, int out_size, void* d_ws, size_t ws_size,
                              hipStream_t stream) {
    const float* x = (const float*)d_in[0];
    const float* weights = (const float*)d_in[1];
    const void* ens = d_in[2];
    const float* pin = (const float*)d_in[3];
    const float* pout = (const float*)d_in[4];
    float* out = (float*)d_out;

    char* ws = (char*)d_ws;
    int*   meta    = (int*)(ws);             // 1 KB
    int*   tok     = (int*)(ws + 1024);      // 20 KB
    float* wgt     = (float*)(ws + 21504);   // 20 KB -> 41984
    int*   inv     = (int*)(ws + 41984);     // 16 KB -> 58368
    u16*   x_bf    = (u16*)(ws + 58368);     // 4 MB  -> 4252672
    u16*   pin_bf  = (u16*)(ws + 4252672);   // 33.5 MB -> 37807104
    u16*   pout_bf = (u16*)(ws + 37807104);  // 33.5 MB -> 71361536
    u16*   h       = (u16*)(ws + 71361536);  // 20 MB -> 92333056 total
    // o_slot overlays pin_bf (dead after gemm1): 5120*1024*4 = 20 MB <= 33.5
    float* o_slot  = (float*)(ws + 4252672);

    // A: convert x + pin; last block buckets assignments + builds inv
    convert_setup<<<dim3(CVA_TOTAL + 1), dim3(256), 0, stream>>>(
        x, pin, x_bf, pin_bf, ens, weights, meta, tok, wgt, inv);

    // B: gemm1 (192 fat blocks) + pout conversion (2048 light blocks)
    gemm1<<<dim3(GRID1 + CVH_P), dim3(THREADS), 0, stream>>>(
        x_bf, pin_bf, meta, tok, h, pout, pout_bf);

    // C: gemm2 -> o_slot (no atomics)
    gemm2<<<dim3(8 * 3 * 8), dim3(THREADS), 0, stream>>>(
        h, pout_bf, meta, o_slot);

    // D: gated combine (overwrites all of d_out; no memset needed)
    reduce_out<<<dim3(NTOK), dim3(256), 0, stream>>>(o_slot, inv, wgt, out);
}